// Round 14
// baseline (190.364 us; speedup 1.0000x reference)
//
#include <hip/hip_runtime.h>
#include <math.h>

typedef __bf16 bf16;
typedef __bf16 bf16x4 __attribute__((ext_vector_type(4)));
typedef __bf16 bf16x8 __attribute__((ext_vector_type(8)));
typedef float floatx4 __attribute__((ext_vector_type(4)));

#define BB 2
#define NN 2048
#define DD 512
#define HH 8
#define HD 64
#define RR 64
#define D3 1536
#define NEG_BIG (-1e30f)
#define TQ 32
#define TBAND 160

// async global->LDS, 16B per lane; LDS dest must be wave-uniform base + lane*16
#define GL2LDS16(g, l)                                                        \
    __builtin_amdgcn_global_load_lds(                                         \
        (const __attribute__((address_space(1))) void*)(const void*)(g),      \
        (__attribute__((address_space(3))) void*)(void*)(l), 16, 0, 0)

// ---------------------------------------------------------------- reductions
static __device__ __forceinline__ float block_reduce_sum256(float v, float* sbuf) {
    const int tid = threadIdx.x;
    #pragma unroll
    for (int o = 32; o > 0; o >>= 1) v += __shfl_xor(v, o, 64);
    __syncthreads();
    if ((tid & 63) == 0) sbuf[tid >> 6] = v;
    __syncthreads();
    return sbuf[0] + sbuf[1] + sbuf[2] + sbuf[3];
}

static __device__ __forceinline__ void ln_row(
    float* sbuf, const float* in, const float* gw, const float* bw,
    bf16* out, float* invnorm, int row, bool want_inv) {
    const int tid = threadIdx.x;
    const int i0 = tid * 2;
    const float* ip = in + (size_t)row * DD;
    float v0 = ip[i0], v1 = ip[i0 + 1];
    float mean = block_reduce_sum256(v0 + v1, sbuf) * (1.f / DD);
    float d0 = v0 - mean, d1 = v1 - mean;
    float var = block_reduce_sum256(d0 * d0 + d1 * d1, sbuf) * (1.f / DD);
    float rs = rsqrtf(var + 1e-5f);
    float x0 = d0 * rs * gw[i0] + bw[i0];
    float x1 = d1 * rs * gw[i0 + 1] + bw[i0 + 1];
    out[(size_t)row * DD + i0] = (bf16)x0;
    out[(size_t)row * DD + i0 + 1] = (bf16)x1;
    if (want_inv) {
        float s2 = block_reduce_sum256(x0 * x0 + x1 * x1, sbuf);
        if (tid == 0) invnorm[row] = 1.f / fmaxf(sqrtf(s2), 1e-12f);
    }
}

// ----------------------------------------------- kernel 1: weight cvt + ln1
union SMemCL {
    bf16 Ts[64][72];
    float sbuf[4];
};
__global__ __launch_bounds__(256) void cvt_ln_kernel(
    const float* __restrict__ qkv_w, const float* __restrict__ proj_w,
    const float* __restrict__ m1w, const float* __restrict__ m2w,
    bf16* __restrict__ wqt, bf16* __restrict__ wpt,
    bf16* __restrict__ w1t, bf16* __restrict__ w2t,
    const float* __restrict__ nodes, const float* __restrict__ ln1_g,
    const float* __restrict__ ln1_b, bf16* __restrict__ x,
    float* __restrict__ invn) {
    __shared__ SMemCL sm;
    const int tid = threadIdx.x;
    int bid = blockIdx.x;
    if (bid >= 512) {                       // LN half
        int r0 = (bid - 512) * 8;
        for (int r = 0; r < 8; r++)
            ln_row(sm.sbuf, nodes, ln1_g, ln1_b, x, invn, r0 + r, true);
        return;
    }
    const float* W; bf16* Wt; int K, N, bx, by;
    if (bid < 192)      { W = qkv_w; Wt = wqt; K = 512;  N = 1536; bx = bid % 24; by = bid / 24; }
    else if (bid < 256) { bid -= 192; W = proj_w; Wt = wpt; K = 512;  N = 512;  bx = bid % 8;  by = bid / 8; }
    else if (bid < 384) { bid -= 256; W = m1w; Wt = w1t; K = 512;  N = 1024; bx = bid % 16; by = bid / 16; }
    else                { bid -= 384; W = m2w; Wt = w2t; K = 1024; N = 512;  bx = bid % 8;  by = bid / 8; }
    const int n0 = bx * 64, k0 = by * 64;
    #pragma unroll
    for (int i = 0; i < 4; i++) {
        int r = (tid >> 4) + i * 16;
        int c = (tid & 15) * 4;
        floatx4 v = *(const floatx4*)(W + (size_t)(k0 + r) * N + n0 + c);
        #pragma unroll
        for (int e = 0; e < 4; e++) sm.Ts[r][c + e] = (bf16)v[e];
    }
    __syncthreads();
    #pragma unroll
    for (int i = 0; i < 4; i++) {
        int n = (tid >> 4) + i * 16;
        int k = (tid & 15) * 4;
        bf16x4 o;
        #pragma unroll
        for (int e = 0; e < 4; e++) o[e] = sm.Ts[k + e][n];
        *(bf16x4*)(Wt + (size_t)(n0 + n) * K + k0 + k) = o;
    }
}

// -------------------------------------- 128x128 GEMM body (m97 structure)
// C[128,128] tile, BK=64, single-buffer LDS (32 KB), 3-bit granule XOR
// swizzle (fragment ds_read_b128 lands 2 lanes/bank-group = free).
// MODE: 0 bias->bf16 | 1 +resid f32->f32 | 2 gelu->bf16 | 3 +resid ->f32
template <int MODE>
static __device__ __forceinline__ void gemm128_body(
    bf16* As, bf16* Bs, const bf16* A, const bf16* Bt,
    const float* bias, const float* resid, void* out,
    int N, int K, int bx, int by) {
    const int tid = threadIdx.x;
    const int w = tid >> 6, lane = tid & 63;
    const int lr = lane & 15, lq = lane >> 4;
    const int rowBase = by * 128, colBase = bx * 128;
    const int wm = (w >> 1) * 64, wn = (w & 1) * 64;

    floatx4 acc[4][4];
    #pragma unroll
    for (int i = 0; i < 4; i++)
        #pragma unroll
        for (int j = 0; j < 4; j++) acc[i][j] = (floatx4){0.f, 0.f, 0.f, 0.f};

    for (int k0 = 0; k0 < K; k0 += 64) {
        __syncthreads();                   // prev compute done, LDS reusable
        #pragma unroll
        for (int i = 0; i < 4; i++) {      // A: 128 rows x 8 granules = 1024
            int g = i * 256 + tid;
            int row = g >> 3, k8 = (g & 7) ^ (row & 7);
            GL2LDS16(A + (size_t)(rowBase + row) * K + k0 + k8 * 8, As + g * 8);
        }
        #pragma unroll
        for (int i = 0; i < 4; i++) {      // B: 128 cols x 8 granules
            int g = i * 256 + tid;
            int row = g >> 3, k8 = (g & 7) ^ (row & 7);
            GL2LDS16(Bt + (size_t)(colBase + row) * K + k0 + k8 * 8, Bs + g * 8);
        }
        __syncthreads();                   // drain vmcnt: LDS ready
        #pragma unroll
        for (int kb = 0; kb < 2; kb++) {
            bf16x8 af[4], bfr[4];
            #pragma unroll
            for (int i = 0; i < 4; i++) {
                int row = wm + i * 16 + lr;
                int g = row * 8 + ((kb * 4 + lq) ^ (row & 7));
                af[i] = *(bf16x8*)&As[g * 8];
            }
            #pragma unroll
            for (int j = 0; j < 4; j++) {
                int row = wn + j * 16 + lr;
                int g = row * 8 + ((kb * 4 + lq) ^ (row & 7));
                bfr[j] = *(bf16x8*)&Bs[g * 8];
            }
            #pragma unroll
            for (int i = 0; i < 4; i++)
                #pragma unroll
                for (int j = 0; j < 4; j++)
                    acc[i][j] = __builtin_amdgcn_mfma_f32_16x16x32_bf16(
                        af[i], bfr[j], acc[i][j], 0, 0, 0);
        }
    }

    #pragma unroll
    for (int i = 0; i < 4; i++) {
        #pragma unroll
        for (int j = 0; j < 4; j++) {
            #pragma unroll
            for (int r = 0; r < 4; r++) {
                int row = rowBase + wm + i * 16 + lq * 4 + r;
                int col = colBase + wn + j * 16 + lr;
                size_t idx = (size_t)row * N + col;
                float v = acc[i][j][r] + bias[col];
                if (MODE == 0) {
                    ((bf16*)out)[idx] = (bf16)v;
                } else if (MODE == 1) {
                    ((float*)out)[idx] = v + resid[idx];
                } else if (MODE == 2) {
                    float g = 0.5f * v * (1.f + erff(v * 0.70710678118654752f));
                    ((bf16*)out)[idx] = (bf16)g;
                } else {
                    ((float*)out)[idx] = v + resid[idx];
                }
            }
        }
    }
}

template <int MODE>
__global__ __launch_bounds__(256) void gemm128_kernel(
    const bf16* __restrict__ A, const bf16* __restrict__ Bt,
    const float* __restrict__ bias, const float* __restrict__ resid,
    void* __restrict__ out, int N, int K) {
    __shared__ __align__(16) bf16 As[128 * 64];
    __shared__ __align__(16) bf16 Bs[128 * 64];
    gemm128_body<MODE>(As, Bs, A, Bt, bias, resid, out, N, K,
                       blockIdx.x, blockIdx.y);
}

// --------------------------------------- kernel 2: corr (head) + qkv GEMM
// grid 512: bid<128 -> corr tile; bid>=128 -> 128x128 qkv gemm tile (384).
union SMemQC {
    struct { bf16 As[128 * 64], Bs[128 * 64]; } g;        // 32 KB
    struct { bf16 Xc[TBAND * 72]; float invb[TBAND]; } c; // 23.7 KB
};
__global__ __launch_bounds__(256) void qkv_corr_kernel(
    const bf16* __restrict__ x, const bf16* __restrict__ wqt,
    const float* __restrict__ qkv_b, const float* __restrict__ invn,
    bf16* __restrict__ qkvb, float* __restrict__ corr_g) {
    __shared__ SMemQC sm;
    const int tid = threadIdx.x;
    const int bid = blockIdx.x;
    const int w = tid >> 6, lane = tid & 63;
    const int lr = lane & 15, lq = lane >> 4;

    if (bid < 128) {                       // ---- corr tile (dispatch head)
        const int item = bid;
        const int b = item & 1, n0 = (item >> 1) * TQ;
        const int bN = b * NN;
        const int rowHalf = (w >> 1) * 16, colBase = (w & 1) * 80;
        if (tid < TBAND) {
            int mc = min(max(n0 - RR + tid, 0), NN - 1);
            sm.c.invb[tid] = invn[bN + mc];
        }
        floatx4 cacc[5];
        #pragma unroll
        for (int t = 0; t < 5; t++) cacc[t] = (floatx4){0.f, 0.f, 0.f, 0.f};
        for (int c = 0; c < 8; c++) {
            __syncthreads();
            #pragma unroll
            for (int rr = 0; rr < 6; rr++) {
                int G = rr * 256 + tid;
                if (G < 1440) {
                    int j = G / 9, gc = G % 9;
                    int gcs = min(gc, 7);
                    int mc = min(max(n0 - RR + j, 0), NN - 1);
                    GL2LDS16(x + (size_t)(bN + mc) * DD + c * 64 + gcs * 8, sm.c.Xc + G * 8);
                }
            }
            __syncthreads();
            #pragma unroll
            for (int kb = 0; kb < 2; kb++) {
                bf16x8 a = *(bf16x8*)&sm.c.Xc[(64 + rowHalf + lr) * 72 + kb * 32 + lq * 8];
                #pragma unroll
                for (int t = 0; t < 5; t++) {
                    bf16x8 bb = *(bf16x8*)&sm.c.Xc[(colBase + t * 16 + lr) * 72 + kb * 32 + lq * 8];
                    cacc[t] = __builtin_amdgcn_mfma_f32_16x16x32_bf16(a, bb, cacc[t], 0, 0, 0);
                }
            }
        }
        float invq[4];
        #pragma unroll
        for (int r = 0; r < 4; r++) invq[r] = sm.c.invb[64 + rowHalf + lq * 4 + r];
        const size_t cbase = (size_t)item * TQ * TBAND;
        #pragma unroll
        for (int t = 0; t < 5; t++) {
            float invk = sm.c.invb[colBase + t * 16 + lr];
            #pragma unroll
            for (int r = 0; r < 4; r++)
                corr_g[cbase + (size_t)(rowHalf + lq * 4 + r) * TBAND + colBase + t * 16 + lr] =
                    cacc[t][r] * invq[r] * invk;
        }
        return;
    }

    const int idx = bid - 128;             // ---- qkv gemm tile
    gemm128_body<0>(sm.g.As, sm.g.Bs, x, wqt, qkv_b, nullptr, qkvb,
                    D3, DD, idx % 12, idx / 12);
}

// --------------------------------------------------------- V transpose kernel
// qkvb V-part [4096][2*DD + h*64+d] -> vt_g[(h*64+d)][4096]
__global__ __launch_bounds__(256) void vtrans_kernel(
    const bf16* __restrict__ qkvb, bf16* __restrict__ vt_g) {
    __shared__ bf16 Ts[64][72];
    const int tid = threadIdx.x;
    const int r0 = blockIdx.x * 64;
    const int h = blockIdx.y;
    #pragma unroll
    for (int i = 0; i < 2; i++) {
        int r = (tid >> 3) + i * 32, c8 = tid & 7;
        *(bf16x8*)&Ts[r][c8 * 8] =
            *(const bf16x8*)(qkvb + (size_t)(r0 + r) * D3 + 2 * DD + h * HD + c8 * 8);
    }
    __syncthreads();
    #pragma unroll
    for (int i = 0; i < 2; i++) {
        int d = (tid >> 3) + i * 32, c8 = (tid & 7) * 8;
        bf16x8 o;
        #pragma unroll
        for (int e = 0; e < 8; e++) o[e] = Ts[c8 + e][d];
        *(bf16x8*)(vt_g + (((size_t)(h * HD + d)) << 12) + r0 + c8) = o;
    }
}

// ---------------------------------------------------------------- LayerNorm2
__global__ __launch_bounds__(256) void ln2_kernel(
    const float* __restrict__ in, const float* __restrict__ gw,
    const float* __restrict__ bw, bf16* __restrict__ out) {
    __shared__ float sbuf[4];
    ln_row(sbuf, in, gw, bw, out, nullptr, blockIdx.x, false);
}

// ---------------------------------------------------------------- attention
// grid 512: b(2) x head-pair(4) x n0(64), 2 heads per block.
__global__ __launch_bounds__(256) void attn_kernel(
    const bf16* __restrict__ qkv, const bf16* __restrict__ vt_g,
    const float* __restrict__ corr_g, const float* __restrict__ rep_scale,
    const float* __restrict__ rel_bias, bf16* __restrict__ upd) {
    __shared__ __align__(16) bf16 Qs[TQ * 136];
    __shared__ __align__(16) bf16 Ks[TBAND * 72];
    __shared__ __align__(16) bf16 Vt[64 * 168];
    __shared__ __align__(16) bf16 Ps[TQ * 168];
    __shared__ float relb[2][192];
    __shared__ float rmax2[TQ][2];
    __shared__ float rsum2[TQ][2];

    const int tid = threadIdx.x;
    const int item = blockIdx.x;
    const int b = item & 1;
    const int h0 = ((item >> 1) & 3) * 2;
    const int n0 = (item >> 3) * TQ;
    const int bN = b * NN;
    const int w = tid >> 6, lane = tid & 63;
    const int lr = lane & 15, lq = lane >> 4;
    const int rowHalf = (w >> 1) * 16;
    const int colBase = (w & 1) * 80;
    const int c2 = (w & 1) * 32;

    for (int idx = tid; idx < 2 * 191; idx += 256) {
        int hh = idx / 191, dh = idx - hh * 191;
        relb[hh][dh] = rel_bias[(size_t)(dh + (NN - 1 - 95)) * HH + h0 + hh];
    }

    float corrv[5][4];
    {
        const size_t cbase = (size_t)((((item >> 3)) << 1) | b) * TQ * TBAND;
        #pragma unroll
        for (int t = 0; t < 5; t++)
            #pragma unroll
            for (int r = 0; r < 4; r++)
                corrv[t][r] = corr_g[cbase + (size_t)(rowHalf + lq * 4 + r) * TBAND +
                                     colBase + t * 16 + lr];
    }

    // stage Q (2 heads): 32 rows x 17 granules = 544
    #pragma unroll
    for (int rr = 0; rr < 3; rr++) {
        int G = rr * 256 + tid;
        if (G < 544) {
            int q = G / 17, gc = G % 17;
            int gcs = min(gc, 15);
            GL2LDS16(qkv + (size_t)(bN + n0 + q) * D3 + h0 * HD + gcs * 8, Qs + G * 8);
        }
    }

    for (int h = h0; h < h0 + 2; h++) {
        __syncthreads();
        #pragma unroll
        for (int rr = 0; rr < 6; rr++) {          // K: 160 x 9 granules
            int G = rr * 256 + tid;
            if (G < 1440) {
                int j = G / 9, gc = G % 9;
                int gcs = min(gc, 7);
                int mc = min(max(n0 - RR + j, 0), NN - 1);
                GL2LDS16(qkv + (size_t)(bN + mc) * D3 + DD + h * HD + gcs * 8, Ks + G * 8);
            }
        }
        #pragma unroll
        for (int rr = 0; rr < 6; rr++) {          // V^T: 64 x 21 granules
            int G = rr * 256 + tid;
            if (G < 1344) {
                int d = G / 21, gc = G % 21;
                int nsrc = min(max(n0 - RR + gc * 8, 0), NN - 8);
                GL2LDS16(vt_g + (((size_t)(h * HD + d)) << 12) + bN + nsrc, Vt + G * 8);
            }
        }
        __syncthreads();

        floatx4 sacc[5];
        #pragma unroll
        for (int t = 0; t < 5; t++) sacc[t] = (floatx4){0.f, 0.f, 0.f, 0.f};
        #pragma unroll
        for (int kb = 0; kb < 2; kb++) {
            bf16x8 a = *(bf16x8*)&Qs[(rowHalf + lr) * 136 + (h - h0) * 64 + kb * 32 + lq * 8];
            #pragma unroll
            for (int t = 0; t < 5; t++) {
                bf16x8 bb = *(bf16x8*)&Ks[(colBase + t * 16 + lr) * 72 + kb * 32 + lq * 8];
                sacc[t] = __builtin_amdgcn_mfma_f32_16x16x32_bf16(a, bb, sacc[t], 0, 0, 0);
            }
        }

        const float srep = rep_scale[h];
        float l[5][4];
        float mx[4] = {NEG_BIG, NEG_BIG, NEG_BIG, NEG_BIG};
        #pragma unroll
        for (int t = 0; t < 5; t++) {
            int j = colBase + t * 16 + lr;
            int m = n0 - RR + j;
            #pragma unroll
            for (int r = 0; r < 4; r++) {
                int qi = rowHalf + lq * 4 + r;
                int relidx = qi + RR - j;
                bool valid = (relidx >= -RR) && (relidx <= RR) && (m >= 0) && (m < NN);
                float lv = sacc[t][r] * 0.125f + corrv[t][r] * srep +
                           relb[h - h0][relidx + 95];
                l[t][r] = valid ? lv : NEG_BIG;
                mx[r] = fmaxf(mx[r], l[t][r]);
            }
        }
        #pragma unroll
        for (int r = 0; r < 4; r++)
            #pragma unroll
            for (int mk = 1; mk <= 8; mk <<= 1)
                mx[r] = fmaxf(mx[r], __shfl_xor(mx[r], mk, 64));
        if (lr == 0) {
            #pragma unroll
            for (int r = 0; r < 4; r++) rmax2[rowHalf + lq * 4 + r][w & 1] = mx[r];
        }
        __syncthreads();

        float rm[4], sme[4];
        #pragma unroll
        for (int r = 0; r < 4; r++) {
            int row = rowHalf + lq * 4 + r;
            rm[r] = fmaxf(rmax2[row][0], rmax2[row][1]);
            sme[r] = 0.f;
        }
        #pragma unroll
        for (int t = 0; t < 5; t++) {
            int j = colBase + t * 16 + lr;
            #pragma unroll
            for (int r = 0; r < 4; r++) {
                float pv = __expf(l[t][r] - rm[r]);
                sme[r] += pv;
                Ps[(rowHalf + lq * 4 + r) * 168 + j] = (bf16)pv;
            }
        }
        #pragma unroll
        for (int r = 0; r < 4; r++)
            #pragma unroll
            for (int mk = 1; mk <= 8; mk <<= 1)
                sme[r] += __shfl_xor(sme[r], mk, 64);
        if (lr == 0) {
            #pragma unroll
            for (int r = 0; r < 4; r++) rsum2[rowHalf + lq * 4 + r][w & 1] = sme[r];
        }
        __syncthreads();

        floatx4 oacc[2] = {(floatx4){0.f, 0.f, 0.f, 0.f}, (floatx4){0.f, 0.f, 0.f, 0.f}};
        #pragma unroll
        for (int kb = 0; kb < 5; kb++) {
            bf16x8 a = *(bf16x8*)&Ps[(rowHalf + lr) * 168 + kb * 32 + lq * 8];
            #pragma unroll
            for (int tt = 0; tt < 2; tt++) {
                bf16x8 bb = *(bf16x8*)&Vt[(c2 + tt * 16 + lr) * 168 + kb * 32 + lq * 8];
                oacc[tt] = __builtin_amdgcn_mfma_f32_16x16x32_bf16(a, bb, oacc[tt], 0, 0, 0);
            }
        }
        #pragma unroll
        for (int r = 0; r < 4; r++) {
            int row = rowHalf + lq * 4 + r;
            float rinv = 1.f / (rsum2[row][0] + rsum2[row][1]);
            #pragma unroll
            for (int tt = 0; tt < 2; tt++) {
                upd[(size_t)(bN + n0 + row) * DD + h * HD + c2 + tt * 16 + lr] =
                    (bf16)(oacc[tt][r] * rinv);
            }
        }
    }
}

// ---------------------------------------------------------------- launch
// Inputs FLOAT32; OUTPUT FLOAT32.  8 kernels; all GEMMs now 128x128/BK=64
// m97-style (the 64x64 tile's 2 MFMA/KB staging ratio was the ~100us sink).
extern "C" void kernel_launch(void* const* d_in, const int* in_sizes, int n_in,
                              void* d_out, int out_size, void* d_ws,
                              size_t ws_size, hipStream_t stream) {
    const float* nodes  = (const float*)d_in[0];
    const float* ln1_g  = (const float*)d_in[1];
    const float* ln1_b  = (const float*)d_in[2];
    const float* qkv_w  = (const float*)d_in[3];
    const float* qkv_b  = (const float*)d_in[4];
    const float* proj_w = (const float*)d_in[5];
    const float* proj_b = (const float*)d_in[6];
    const float* rep_s  = (const float*)d_in[7];
    const float* rel_b  = (const float*)d_in[8];
    const float* ln2_g  = (const float*)d_in[9];
    const float* ln2_b  = (const float*)d_in[10];
    const float* mlp_w1 = (const float*)d_in[11];
    const float* mlp_b1 = (const float*)d_in[12];
    const float* mlp_w2 = (const float*)d_in[13];
    const float* mlp_b2 = (const float*)d_in[14];

    char* p = (char*)d_ws;
    float* invn = (float*)p;            p += (size_t)1 << 20;
    bf16*  wqt  = (bf16*)p;             p += (size_t)DD * D3 * 2;
    bf16*  wpt  = (bf16*)p;             p += (size_t)DD * DD * 2;
    bf16*  w1t  = (bf16*)p;             p += (size_t)DD * 2 * DD * 2;
    bf16*  w2t  = (bf16*)p;             p += (size_t)2 * DD * DD * 2;
    bf16*  x    = (bf16*)p;             p += (size_t)BB * NN * DD * 2;
    bf16*  qkvb = (bf16*)p;             p += (size_t)BB * NN * D3 * 2;
    char*  regA = p;                    p += (size_t)BB * NN * DD * 4;   // 8 MiB
    float* corr_g = (float*)regA;                               // 2.62 MiB
    bf16*  vt_g   = (bf16*)(regA + (size_t)BB * (NN / TQ) * TQ * TBAND * 4);  // 4 MiB
    float* mid    = (float*)regA;   // written by proj after attn consumed overlays
    bf16*  y    = x;                // alias: x dead after qkv_corr
    bf16*  hgl  = qkvb;             // alias: qkvb dead after attn
    bf16*  upd  = (bf16*)d_out;     // consumed by proj; d_out rewritten f32 by mlp2

    const int M = BB * NN;  // 4096

    cvt_ln_kernel<<<1024, 256, 0, stream>>>(
        qkv_w, proj_w, mlp_w1, mlp_w2, wqt, wpt, w1t, w2t,
        nodes, ln1_g, ln1_b, x, invn);
    qkv_corr_kernel<<<512, 256, 0, stream>>>(
        x, wqt, qkv_b, invn, qkvb, corr_g);
    vtrans_kernel<<<dim3(M / 64, HH), 256, 0, stream>>>(qkvb, vt_g);
    attn_kernel<<<512, 256, 0, stream>>>(
        qkvb, vt_g, corr_g, rep_s, rel_b, upd);
    gemm128_kernel<1><<<dim3(DD / 128, M / 128), 256, 0, stream>>>(
        upd, wpt, proj_b, nodes, mid, DD, DD);
    ln2_kernel<<<M, 256, 0, stream>>>(mid, ln2_g, ln2_b, y);
    gemm128_kernel<2><<<dim3(2 * DD / 128, M / 128), 256, 0, stream>>>(
        y, w1t, mlp_b1, nullptr, hgl, 2 * DD, DD);
    gemm128_kernel<3><<<dim3(DD / 128, M / 128), 256, 0, stream>>>(
        hgl, w2t, mlp_b2, mid, (float*)d_out, DD, 2 * DD);
}

// Round 15
// 172.916 us; speedup vs baseline: 1.1009x; 1.1009x over previous
//
#include <hip/hip_runtime.h>
#include <math.h>

typedef __bf16 bf16;
typedef __bf16 bf16x4 __attribute__((ext_vector_type(4)));
typedef __bf16 bf16x8 __attribute__((ext_vector_type(8)));
typedef float floatx4 __attribute__((ext_vector_type(4)));

#define BB 2
#define NN 2048
#define DD 512
#define HH 8
#define HD 64
#define RR 64
#define D3 1536
#define NEG_BIG (-1e30f)
#define TQ 32
#define TBAND 160

// async global->LDS, 16B per lane; LDS dest must be wave-uniform base + lane*16
#define GL2LDS16(g, l)                                                        \
    __builtin_amdgcn_global_load_lds(                                         \
        (const __attribute__((address_space(1))) void*)(const void*)(g),      \
        (__attribute__((address_space(3))) void*)(void*)(l), 16, 0, 0)

// ------------------------------------------------- wave-parallel LayerNorm
// One wave owns one row: lane l holds cols l*8..l*8+7; shuffle-only reduce.
static __device__ __forceinline__ void ln_row_wave(
    const float* __restrict__ in, const float* __restrict__ gw,
    const float* __restrict__ bw, bf16* __restrict__ out,
    float* __restrict__ invnorm, int row, bool want_inv) {
    const int lane = threadIdx.x & 63;
    const float* ip = in + (size_t)row * DD + lane * 8;
    floatx4 a = *(const floatx4*)ip;
    floatx4 b = *(const floatx4*)(ip + 4);
    float s = a[0] + a[1] + a[2] + a[3] + b[0] + b[1] + b[2] + b[3];
    #pragma unroll
    for (int o = 1; o < 64; o <<= 1) s += __shfl_xor(s, o, 64);
    const float mean = s * (1.f / DD);
    float v = 0.f;
    #pragma unroll
    for (int e = 0; e < 4; e++) { a[e] -= mean; v += a[e] * a[e]; }
    #pragma unroll
    for (int e = 0; e < 4; e++) { b[e] -= mean; v += b[e] * b[e]; }
    #pragma unroll
    for (int o = 1; o < 64; o <<= 1) v += __shfl_xor(v, o, 64);
    const float rs = rsqrtf(v * (1.f / DD) + 1e-5f);
    floatx4 g0 = *(const floatx4*)(gw + lane * 8);
    floatx4 g1 = *(const floatx4*)(gw + lane * 8 + 4);
    floatx4 b0 = *(const floatx4*)(bw + lane * 8);
    floatx4 b1 = *(const floatx4*)(bw + lane * 8 + 4);
    float x[8];
    #pragma unroll
    for (int e = 0; e < 4; e++) {
        x[e] = a[e] * rs * g0[e] + b0[e];
        x[4 + e] = b[e] * rs * g1[e] + b1[e];
    }
    bf16x8 o8;
    #pragma unroll
    for (int e = 0; e < 8; e++) o8[e] = (bf16)x[e];
    *(bf16x8*)(out + (size_t)row * DD + lane * 8) = o8;
    if (want_inv) {
        float s2 = 0.f;
        #pragma unroll
        for (int e = 0; e < 8; e++) s2 += x[e] * x[e];
        #pragma unroll
        for (int o = 1; o < 64; o <<= 1) s2 += __shfl_xor(s2, o, 64);
        if (lane == 0) invnorm[row] = 1.f / fmaxf(sqrtf(s2), 1e-12f);
    }
}

// ----------------------------------------------- kernel 1: weight cvt + ln1
// grid 1024: bid<512 -> one 64x64 cvt+transpose tile; else 8 LN rows (wave-par).
__global__ __launch_bounds__(256) void cvt_ln_kernel(
    const float* __restrict__ qkv_w, const float* __restrict__ proj_w,
    const float* __restrict__ m1w, const float* __restrict__ m2w,
    bf16* __restrict__ wqt, bf16* __restrict__ wpt,
    bf16* __restrict__ w1t, bf16* __restrict__ w2t,
    const float* __restrict__ nodes, const float* __restrict__ ln1_g,
    const float* __restrict__ ln1_b, bf16* __restrict__ x,
    float* __restrict__ invn) {
    __shared__ bf16 Ts[64][72];
    const int tid = threadIdx.x;
    int bid = blockIdx.x;
    if (bid >= 512) {                       // LN half: 8 rows, 4 waves x 2
        int r0 = (bid - 512) * 8 + (tid >> 6) * 2;
        ln_row_wave(nodes, ln1_g, ln1_b, x, invn, r0, true);
        ln_row_wave(nodes, ln1_g, ln1_b, x, invn, r0 + 1, true);
        return;
    }
    const float* W; bf16* Wt; int K, N, bx, by;
    if (bid < 192)      { W = qkv_w; Wt = wqt; K = 512;  N = 1536; bx = bid % 24; by = bid / 24; }
    else if (bid < 256) { bid -= 192; W = proj_w; Wt = wpt; K = 512;  N = 512;  bx = bid % 8;  by = bid / 8; }
    else if (bid < 384) { bid -= 256; W = m1w; Wt = w1t; K = 512;  N = 1024; bx = bid % 16; by = bid / 16; }
    else                { bid -= 384; W = m2w; Wt = w2t; K = 1024; N = 512;  bx = bid % 8;  by = bid / 8; }
    const int n0 = bx * 64, k0 = by * 64;
    #pragma unroll
    for (int i = 0; i < 4; i++) {
        int r = (tid >> 4) + i * 16;
        int c = (tid & 15) * 4;
        floatx4 v = *(const floatx4*)(W + (size_t)(k0 + r) * N + n0 + c);
        #pragma unroll
        for (int e = 0; e < 4; e++) Ts[r][c + e] = (bf16)v[e];
    }
    __syncthreads();
    #pragma unroll
    for (int i = 0; i < 4; i++) {
        int n = (tid >> 4) + i * 16;
        int k = (tid & 15) * 4;
        bf16x4 o;
        #pragma unroll
        for (int e = 0; e < 4; e++) o[e] = Ts[k + e][n];
        *(bf16x4*)(Wt + (size_t)(n0 + n) * K + k0 + k) = o;
    }
}

// --------------------------------------- kernel 2: corr + qkv GEMM (+V^T)
// grid 1664: bid<128 -> corr tile (dispatched first: longest items lead);
// bid>=128 -> 64x64 dbuf gemm tile; V columns (bx>=16) transpose -> vt_g.
union SMemQC {
    struct { bf16 As[2][4096], Bs[2][4096]; } g;          // 32 KB
    struct { bf16 Ts[64][72]; } t;     // aliases g; used only after K-loop+sync
    struct { bf16 Xc[TBAND * 72]; float invb[TBAND]; } c; // 23.7 KB
};
__global__ __launch_bounds__(256) void qkv_corr_kernel(
    const bf16* __restrict__ x, const bf16* __restrict__ wqt,
    const float* __restrict__ qkv_b, const float* __restrict__ invn,
    bf16* __restrict__ qkvb, bf16* __restrict__ vt_g,
    float* __restrict__ corr_g) {
    __shared__ SMemQC sm;
    const int tid = threadIdx.x;
    const int bid = blockIdx.x;
    const int w = tid >> 6, lane = tid & 63;
    const int lr = lane & 15, lq = lane >> 4;

    if (bid < 128) {                       // ---- corr tile
        const int item = bid;
        const int b = item & 1, n0 = (item >> 1) * TQ;
        const int bN = b * NN;
        const int rowHalf = (w >> 1) * 16, colBase = (w & 1) * 80;
        if (tid < TBAND) {
            int mc = min(max(n0 - RR + tid, 0), NN - 1);
            sm.c.invb[tid] = invn[bN + mc];
        }
        floatx4 cacc[5];
        #pragma unroll
        for (int t = 0; t < 5; t++) cacc[t] = (floatx4){0.f, 0.f, 0.f, 0.f};
        for (int c = 0; c < 8; c++) {
            __syncthreads();
            #pragma unroll
            for (int rr = 0; rr < 6; rr++) {
                int G = rr * 256 + tid;
                if (G < 1440) {
                    int j = G / 9, gc = G % 9;
                    int gcs = min(gc, 7);
                    int mc = min(max(n0 - RR + j, 0), NN - 1);
                    GL2LDS16(x + (size_t)(bN + mc) * DD + c * 64 + gcs * 8, sm.c.Xc + G * 8);
                }
            }
            __syncthreads();
            #pragma unroll
            for (int kb = 0; kb < 2; kb++) {
                bf16x8 a = *(bf16x8*)&sm.c.Xc[(64 + rowHalf + lr) * 72 + kb * 32 + lq * 8];
                #pragma unroll
                for (int t = 0; t < 5; t++) {
                    bf16x8 bb = *(bf16x8*)&sm.c.Xc[(colBase + t * 16 + lr) * 72 + kb * 32 + lq * 8];
                    cacc[t] = __builtin_amdgcn_mfma_f32_16x16x32_bf16(a, bb, cacc[t], 0, 0, 0);
                }
            }
        }
        float invq[4];
        #pragma unroll
        for (int r = 0; r < 4; r++) invq[r] = sm.c.invb[64 + rowHalf + lq * 4 + r];
        const size_t cbase = (size_t)item * TQ * TBAND;
        #pragma unroll
        for (int t = 0; t < 5; t++) {
            float invk = sm.c.invb[colBase + t * 16 + lr];
            #pragma unroll
            for (int r = 0; r < 4; r++)
                corr_g[cbase + (size_t)(rowHalf + lq * 4 + r) * TBAND + colBase + t * 16 + lr] =
                    cacc[t][r] * invq[r] * invk;
        }
        return;
    }

    // ---- gemm tile (A = x [4096][512], Bt = wqt [1536][512])
    const int g2 = bid - 128;
    const int bx = g2 % 24, by = g2 / 24;
    const int rowBase = by * 64, colBase = bx * 64;
    const int wm = (w >> 1) * 32, wn = (w & 1) * 32;

    floatx4 acc[2][2];
    #pragma unroll
    for (int i = 0; i < 2; i++)
        #pragma unroll
        for (int j = 0; j < 2; j++) acc[i][j] = (floatx4){0.f, 0.f, 0.f, 0.f};

    auto stage = [&](int buf, int k0) {
        #pragma unroll
        for (int i = 0; i < 2; i++) {
            int g = i * 256 + tid;
            int row = g >> 3, k8 = (g & 7) ^ (row & 7);
            GL2LDS16(x + (size_t)(rowBase + row) * DD + k0 + k8 * 8, &sm.g.As[buf][g * 8]);
        }
        #pragma unroll
        for (int i = 0; i < 2; i++) {
            int g = i * 256 + tid;
            int row = g >> 3, k8 = (g & 7) ^ (row & 7);
            GL2LDS16(wqt + (size_t)(colBase + row) * DD + k0 + k8 * 8, &sm.g.Bs[buf][g * 8]);
        }
    };

    stage(0, 0);
    for (int s = 0; s < 8; s++) {
        __syncthreads();
        if (s + 1 < 8) stage((s + 1) & 1, (s + 1) * 64);
        const int buf = s & 1;
        #pragma unroll
        for (int kb = 0; kb < 2; kb++) {
            bf16x8 af[2], bfr[2];
            #pragma unroll
            for (int i = 0; i < 2; i++) {
                int row = wm + i * 16 + lr;
                int g = row * 8 + ((kb * 4 + lq) ^ (row & 7));
                af[i] = *(bf16x8*)&sm.g.As[buf][g * 8];
            }
            #pragma unroll
            for (int j = 0; j < 2; j++) {
                int row = wn + j * 16 + lr;
                int g = row * 8 + ((kb * 4 + lq) ^ (row & 7));
                bfr[j] = *(bf16x8*)&sm.g.Bs[buf][g * 8];
            }
            #pragma unroll
            for (int i = 0; i < 2; i++)
                #pragma unroll
                for (int j = 0; j < 2; j++)
                    acc[i][j] = __builtin_amdgcn_mfma_f32_16x16x32_bf16(
                        af[i], bfr[j], acc[i][j], 0, 0, 0);
        }
    }

    if (bx < 16) {                         // Q/K columns: store to qkvb
        #pragma unroll
        for (int i = 0; i < 2; i++)
            #pragma unroll
            for (int j = 0; j < 2; j++)
                #pragma unroll
                for (int r = 0; r < 4; r++) {
                    int row = rowBase + wm + i * 16 + lq * 4 + r;
                    int col = colBase + wn + j * 16 + lr;
                    qkvb[(size_t)row * D3 + col] = (bf16)(acc[i][j][r] + qkv_b[col]);
                }
    } else {                               // V columns: transpose -> vt_g
        __syncthreads();                   // g.As consumed; reuse as Ts
        #pragma unroll
        for (int i = 0; i < 2; i++)
            #pragma unroll
            for (int j = 0; j < 2; j++)
                #pragma unroll
                for (int r = 0; r < 4; r++) {
                    int nl = wm + i * 16 + lq * 4 + r;
                    int dl = wn + j * 16 + lr;
                    sm.t.Ts[nl][dl] = (bf16)(acc[i][j][r] + qkv_b[colBase + dl]);
                }
        __syncthreads();
        const int dV = colBase - 1024;     // 0..448
        #pragma unroll
        for (int i2 = 0; i2 < 2; i2++) {
            int d = (tid >> 3) + i2 * 32;
            int n8 = (tid & 7) * 8;
            bf16x8 o;
            #pragma unroll
            for (int e = 0; e < 8; e++) o[e] = sm.t.Ts[n8 + e][d];
            *(bf16x8*)(vt_g + (((size_t)(dV + d)) << 12) + rowBase + n8) = o;
        }
    }
}

// --------------------------------------------- GEMM kernels (modes 1,2,3)
//  1: +resid f32->f32 (proj->mid) | 2: gelu->bf16 (mlp1) | 3: +resid ->f32 out
template <int MODE>
__global__ __launch_bounds__(256) void gemm_bt(
    const bf16* __restrict__ A, const bf16* __restrict__ Bt,
    const float* __restrict__ bias, const float* __restrict__ resid,
    void* __restrict__ out, int M, int N, int K) {
    __shared__ __align__(16) bf16 As[2][64 * 64];
    __shared__ __align__(16) bf16 Bs[2][64 * 64];
    const int tid = threadIdx.x;
    const int w = tid >> 6, lane = tid & 63;
    const int lr = lane & 15, lq = lane >> 4;
    const int rowBase = blockIdx.y * 64, colBase = blockIdx.x * 64;
    const int wm = (w >> 1) * 32, wn = (w & 1) * 32;

    floatx4 acc[2][2];
    #pragma unroll
    for (int i = 0; i < 2; i++)
        #pragma unroll
        for (int j = 0; j < 2; j++) acc[i][j] = (floatx4){0.f, 0.f, 0.f, 0.f};

    auto stage = [&](int buf, int k0) {
        #pragma unroll
        for (int i = 0; i < 2; i++) {
            int g = i * 256 + tid;
            int row = g >> 3, k8 = (g & 7) ^ (row & 7);
            GL2LDS16(A + (size_t)(rowBase + row) * K + k0 + k8 * 8, &As[buf][g * 8]);
        }
        #pragma unroll
        for (int i = 0; i < 2; i++) {
            int g = i * 256 + tid;
            int row = g >> 3, k8 = (g & 7) ^ (row & 7);
            GL2LDS16(Bt + (size_t)(colBase + row) * K + k0 + k8 * 8, &Bs[buf][g * 8]);
        }
    };

    const int nsteps = K >> 6;
    stage(0, 0);
    for (int s = 0; s < nsteps; s++) {
        __syncthreads();
        if (s + 1 < nsteps) stage((s + 1) & 1, (s + 1) * 64);
        const int buf = s & 1;
        #pragma unroll
        for (int kb = 0; kb < 2; kb++) {
            bf16x8 af[2], bfr[2];
            #pragma unroll
            for (int i = 0; i < 2; i++) {
                int row = wm + i * 16 + lr;
                int g = row * 8 + ((kb * 4 + lq) ^ (row & 7));
                af[i] = *(bf16x8*)&As[buf][g * 8];
            }
            #pragma unroll
            for (int j = 0; j < 2; j++) {
                int row = wn + j * 16 + lr;
                int g = row * 8 + ((kb * 4 + lq) ^ (row & 7));
                bfr[j] = *(bf16x8*)&Bs[buf][g * 8];
            }
            #pragma unroll
            for (int i = 0; i < 2; i++)
                #pragma unroll
                for (int j = 0; j < 2; j++)
                    acc[i][j] = __builtin_amdgcn_mfma_f32_16x16x32_bf16(
                        af[i], bfr[j], acc[i][j], 0, 0, 0);
        }
    }

    #pragma unroll
    for (int i = 0; i < 2; i++) {
        #pragma unroll
        for (int j = 0; j < 2; j++) {
            #pragma unroll
            for (int r = 0; r < 4; r++) {
                int row = rowBase + wm + i * 16 + lq * 4 + r;
                int col = colBase + wn + j * 16 + lr;
                size_t idx = (size_t)row * N + col;
                float v = acc[i][j][r] + bias[col];
                if (MODE == 1) {
                    ((float*)out)[idx] = v + resid[idx];
                } else if (MODE == 2) {
                    float g = 0.5f * v * (1.f + erff(v * 0.70710678118654752f));
                    ((bf16*)out)[idx] = (bf16)g;
                } else {
                    ((float*)out)[idx] = v + resid[idx];
                }
            }
        }
    }
}

// ---------------------------------------------------------------- LayerNorm2
// grid 1024, 4 rows/block (one per wave), shuffle-only.
__global__ __launch_bounds__(256) void ln2_kernel(
    const float* __restrict__ in, const float* __restrict__ gw,
    const float* __restrict__ bw, bf16* __restrict__ out) {
    ln_row_wave(in, gw, bw, out, nullptr,
                blockIdx.x * 4 + (threadIdx.x >> 6), false);
}

// ---------------------------------------------------------------- attention
// grid 512: b(2) x head-pair(4) x n0(64), 2 heads per block.
__global__ __launch_bounds__(256) void attn_kernel(
    const bf16* __restrict__ qkv, const bf16* __restrict__ vt_g,
    const float* __restrict__ corr_g, const float* __restrict__ rep_scale,
    const float* __restrict__ rel_bias, bf16* __restrict__ upd) {
    __shared__ __align__(16) bf16 Qs[TQ * 136];
    __shared__ __align__(16) bf16 Ks[TBAND * 72];
    __shared__ __align__(16) bf16 Vt[64 * 168];
    __shared__ __align__(16) bf16 Ps[TQ * 168];
    __shared__ float relb[2][192];
    __shared__ float rmax2[TQ][2];
    __shared__ float rsum2[TQ][2];

    const int tid = threadIdx.x;
    const int item = blockIdx.x;
    const int b = item & 1;
    const int h0 = ((item >> 1) & 3) * 2;
    const int n0 = (item >> 3) * TQ;
    const int bN = b * NN;
    const int w = tid >> 6, lane = tid & 63;
    const int lr = lane & 15, lq = lane >> 4;
    const int rowHalf = (w >> 1) * 16;
    const int colBase = (w & 1) * 80;
    const int c2 = (w & 1) * 32;

    for (int idx = tid; idx < 2 * 191; idx += 256) {
        int hh = idx / 191, dh = idx - hh * 191;
        relb[hh][dh] = rel_bias[(size_t)(dh + (NN - 1 - 95)) * HH + h0 + hh];
    }

    float corrv[5][4];
    {
        const size_t cbase = (size_t)((((item >> 3)) << 1) | b) * TQ * TBAND;
        #pragma unroll
        for (int t = 0; t < 5; t++)
            #pragma unroll
            for (int r = 0; r < 4; r++)
                corrv[t][r] = corr_g[cbase + (size_t)(rowHalf + lq * 4 + r) * TBAND +
                                     colBase + t * 16 + lr];
    }

    // stage Q (2 heads): 32 rows x 17 granules = 544
    #pragma unroll
    for (int rr = 0; rr < 3; rr++) {
        int G = rr * 256 + tid;
        if (G < 544) {
            int q = G / 17, gc = G % 17;
            int gcs = min(gc, 15);
            GL2LDS16(qkv + (size_t)(bN + n0 + q) * D3 + h0 * HD + gcs * 8, Qs + G * 8);
        }
    }

    for (int h = h0; h < h0 + 2; h++) {
        __syncthreads();
        #pragma unroll
        for (int rr = 0; rr < 6; rr++) {          // K: 160 x 9 granules
            int G = rr * 256 + tid;
            if (G < 1440) {
                int j = G / 9, gc = G % 9;
                int gcs = min(gc, 7);
                int mc = min(max(n0 - RR + j, 0), NN - 1);
                GL2LDS16(qkv + (size_t)(bN + mc) * D3 + DD + h * HD + gcs * 8, Ks + G * 8);
            }
        }
        #pragma unroll
        for (int rr = 0; rr < 6; rr++) {          // V^T: 64 x 21 granules
            int G = rr * 256 + tid;
            if (G < 1344) {
                int d = G / 21, gc = G % 21;
                int nsrc = min(max(n0 - RR + gc * 8, 0), NN - 8);
                GL2LDS16(vt_g + (((size_t)(h * HD + d)) << 12) + bN + nsrc, Vt + G * 8);
            }
        }
        __syncthreads();

        floatx4 sacc[5];
        #pragma unroll
        for (int t = 0; t < 5; t++) sacc[t] = (floatx4){0.f, 0.f, 0.f, 0.f};
        #pragma unroll
        for (int kb = 0; kb < 2; kb++) {
            bf16x8 a = *(bf16x8*)&Qs[(rowHalf + lr) * 136 + (h - h0) * 64 + kb * 32 + lq * 8];
            #pragma unroll
            for (int t = 0; t < 5; t++) {
                bf16x8 bb = *(bf16x8*)&Ks[(colBase + t * 16 + lr) * 72 + kb * 32 + lq * 8];
                sacc[t] = __builtin_amdgcn_mfma_f32_16x16x32_bf16(a, bb, sacc[t], 0, 0, 0);
            }
        }

        const float srep = rep_scale[h];
        float l[5][4];
        float mx[4] = {NEG_BIG, NEG_BIG, NEG_BIG, NEG_BIG};
        #pragma unroll
        for (int t = 0; t < 5; t++) {
            int j = colBase + t * 16 + lr;
            int m = n0 - RR + j;
            #pragma unroll
            for (int r = 0; r < 4; r++) {
                int qi = rowHalf + lq * 4 + r;
                int relidx = qi + RR - j;
                bool valid = (relidx >= -RR) && (relidx <= RR) && (m >= 0) && (m < NN);
                float lv = sacc[t][r] * 0.125f + corrv[t][r] * srep +
                           relb[h - h0][relidx + 95];
                l[t][r] = valid ? lv : NEG_BIG;
                mx[r] = fmaxf(mx[r], l[t][r]);
            }
        }
        #pragma unroll
        for (int r = 0; r < 4; r++)
            #pragma unroll
            for (int mk = 1; mk <= 8; mk <<= 1)
                mx[r] = fmaxf(mx[r], __shfl_xor(mx[r], mk, 64));
        if (lr == 0) {
            #pragma unroll
            for (int r = 0; r < 4; r++) rmax2[rowHalf + lq * 4 + r][w & 1] = mx[r];
        }
        __syncthreads();

        float rm[4], sme[4];
        #pragma unroll
        for (int r = 0; r < 4; r++) {
            int row = rowHalf + lq * 4 + r;
            rm[r] = fmaxf(rmax2[row][0], rmax2[row][1]);
            sme[r] = 0.f;
        }
        #pragma unroll
        for (int t = 0; t < 5; t++) {
            int j = colBase + t * 16 + lr;
            #pragma unroll
            for (int r = 0; r < 4; r++) {
                float pv = __expf(l[t][r] - rm[r]);
                sme[r] += pv;
                Ps[(rowHalf + lq * 4 + r) * 168 + j] = (bf16)pv;
            }
        }
        #pragma unroll
        for (int r = 0; r < 4; r++)
            #pragma unroll
            for (int mk = 1; mk <= 8; mk <<= 1)
                sme[r] += __shfl_xor(sme[r], mk, 64);
        if (lr == 0) {
            #pragma unroll
            for (int r = 0; r < 4; r++) rsum2[rowHalf + lq * 4 + r][w & 1] = sme[r];
        }
        __syncthreads();

        floatx4 oacc[2] = {(floatx4){0.f, 0.f, 0.f, 0.f}, (floatx4){0.f, 0.f, 0.f, 0.f}};
        #pragma unroll
        for (int kb = 0; kb < 5; kb++) {
            bf16x8 a = *(bf16x8*)&Ps[(rowHalf + lr) * 168 + kb * 32 + lq * 8];
            #pragma unroll
            for (int tt = 0; tt < 2; tt++) {
                bf16x8 bb = *(bf16x8*)&Vt[(c2 + tt * 16 + lr) * 168 + kb * 32 + lq * 8];
                oacc[tt] = __builtin_amdgcn_mfma_f32_16x16x32_bf16(a, bb, oacc[tt], 0, 0, 0);
            }
        }
        #pragma unroll
        for (int r = 0; r < 4; r++) {
            int row = rowHalf + lq * 4 + r;
            float rinv = 1.f / (rsum2[row][0] + rsum2[row][1]);
            #pragma unroll
            for (int tt = 0; tt < 2; tt++) {
                upd[(size_t)(bN + n0 + row) * DD + h * HD + c2 + tt * 16 + lr] =
                    (bf16)(oacc[tt][r] * rinv);
            }
        }
    }
}

// ---------------------------------------------------------------- launch
// Inputs FLOAT32; OUTPUT FLOAT32.  7 kernels; wave-parallel LNs; corr at
// grid head; V^T fused into qkv epilogue.
extern "C" void kernel_launch(void* const* d_in, const int* in_sizes, int n_in,
                              void* d_out, int out_size, void* d_ws,
                              size_t ws_size, hipStream_t stream) {
    const float* nodes  = (const float*)d_in[0];
    const float* ln1_g  = (const float*)d_in[1];
    const float* ln1_b  = (const float*)d_in[2];
    const float* qkv_w  = (const float*)d_in[3];
    const float* qkv_b  = (const float*)d_in[4];
    const float* proj_w = (const float*)d_in[5];
    const float* proj_b = (const float*)d_in[6];
    const float* rep_s  = (const float*)d_in[7];
    const float* rel_b  = (const float*)d_in[8];
    const float* ln2_g  = (const float*)d_in[9];
    const float* ln2_b  = (const float*)d_in[10];
    const float* mlp_w1 = (const float*)d_in[11];
    const float* mlp_b1 = (const float*)d_in[12];
    const float* mlp_w2 = (const float*)d_in[13];
    const float* mlp_b2 = (const float*)d_in[14];

    char* p = (char*)d_ws;
    float* invn = (float*)p;            p += (size_t)1 << 20;
    bf16*  wqt  = (bf16*)p;             p += (size_t)DD * D3 * 2;
    bf16*  wpt  = (bf16*)p;             p += (size_t)DD * DD * 2;
    bf16*  w1t  = (bf16*)p;             p += (size_t)DD * 2 * DD * 2;
    bf16*  w2t  = (bf16*)p;             p += (size_t)2 * DD * DD * 2;
    bf16*  x    = (bf16*)p;             p += (size_t)BB * NN * DD * 2;
    bf16*  qkvb = (bf16*)p;             p += (size_t)BB * NN * D3 * 2;
    char*  regA = p;                    p += (size_t)BB * NN * DD * 4;   // 8 MiB
    float* corr_g = (float*)regA;                               // 2.62 MiB
    bf16*  vt_g   = (bf16*)(regA + (size_t)BB * (NN / TQ) * TQ * TBAND * 4);  // 4 MiB
    float* mid    = (float*)regA;   // written by proj after attn consumed overlays
    bf16*  y    = x;                // alias: x dead after qkv_corr
    bf16*  hgl  = qkvb;             // alias: qkvb dead after attn
    bf16*  upd  = (bf16*)d_out;     // consumed by proj; d_out rewritten f32 by mlp2

    const int M = BB * NN;  // 4096

    cvt_ln_kernel<<<1024, 256, 0, stream>>>(
        qkv_w, proj_w, mlp_w1, mlp_w2, wqt, wpt, w1t, w2t,
        nodes, ln1_g, ln1_b, x, invn);
    qkv_corr_kernel<<<1664, 256, 0, stream>>>(
        x, wqt, qkv_b, invn, qkvb, vt_g, corr_g);
    attn_kernel<<<512, 256, 0, stream>>>(
        qkvb, vt_g, corr_g, rep_s, rel_b, upd);
    gemm_bt<1><<<dim3(DD / 64, M / 64), 256, 0, stream>>>(
        upd, wpt, proj_b, nodes, mid, M, DD, DD);
    ln2_kernel<<<1024, 256, 0, stream>>>(mid, ln2_g, ln2_b, y);
    gemm_bt<2><<<dim3(2 * DD / 64, M / 64), 256, 0, stream>>>(
        y, w1t, mlp_b1, nullptr, hgl, M, 2 * DD, DD);
    gemm_bt<3><<<dim3(DD / 64, M / 64), 256, 0, stream>>>(
        hgl, w2t, mlp_b2, mid, (float*)d_out, M, DD, 2 * DD);
}